// Round 18
// baseline (484.268 us; speedup 1.0000x reference)
//
#include <hip/hip_runtime.h>
#include <hip/hip_bf16.h>
#include <cstdint>

#define H_  1024
#define NH_ 16
#define DH_ 64
#define I_  4096
#define E_  8
#define B_  2
#define S_  2048
#define N_  4096        // B_*S_
#define QKVLD 3072      // fused qkv row stride
#define LN_EPS 1e-12f

typedef __attribute__((ext_vector_type(4))) float f4;
typedef __attribute__((ext_vector_type(8))) short s8v;
typedef unsigned int u32;

// ---------- helpers ----------
__device__ __forceinline__ float bf2f(unsigned short u) {
  union { unsigned int i; float f; } c; c.i = ((unsigned int)u) << 16; return c.f;
}
__device__ __forceinline__ unsigned short f2bf(float f) {
  __hip_bfloat16 h = __float2bfloat16(f);
  return *reinterpret_cast<unsigned short*>(&h);
}
__device__ __forceinline__ u32 pack_bf2(float a, float b) {
  return (u32)f2bf(a) | ((u32)f2bf(b) << 16);
}
__device__ __forceinline__ float gelu_f(float x) {
  return 0.5f * x * (1.0f + erff(x * 0.70710678118f));   // exact GELU
}
__device__ __forceinline__ void gload16(const void* g, void* l) {
  __builtin_amdgcn_global_load_lds(
      (const __attribute__((address_space(1))) void*)g,
      (__attribute__((address_space(3))) void*)l, 16, 0, 0);
}

// ---------- fp32 -> bf16 elementwise (+ zero expert counters) ----------
__global__ __launch_bounds__(256) void cvt_bf16_kernel(
    const float* __restrict__ in, ushort* __restrict__ out, int n8, int* __restrict__ cnt)
{
  if (blockIdx.x == 0 && threadIdx.x < E_) cnt[threadIdx.x] = 0;
  const int t = blockIdx.x * 256 + threadIdx.x;
  if (t >= n8) return;
  const f4 x0 = *(const f4*)(in + (size_t)t * 8);
  const f4 x1 = *(const f4*)(in + (size_t)t * 8 + 4);
  s8v o;
#pragma unroll
  for (int j = 0; j < 4; ++j) { o[j] = (short)f2bf(x0[j]); o[4 + j] = (short)f2bf(x1[j]); }
  *(s8v*)(out + (size_t)t * 8) = o;
}

// ---------- fp32 [R][C] -> bf16 [C][R] transpose, 64x64 tile, 16B stores ----
__device__ __forceinline__ void transpose_body(
    const float* __restrict__ in, ushort* __restrict__ out, int R, int C)
{
  __shared__ float Ls[64][68];
  const int bx = blockIdx.x << 6;   // col base
  const int by = blockIdx.y << 6;   // row base
  const int tid = threadIdx.x;
  const int lr = tid >> 4, lc4 = (tid & 15) << 2;
  const float* ip = in + (size_t)(by + lr) * C + bx + lc4;
#pragma unroll
  for (int i = 0; i < 4; ++i)
    *(f4*)&Ls[lr + (i << 4)][lc4] = *(const f4*)(ip + (size_t)(i << 4) * C);
  __syncthreads();
  const int oc = tid >> 2, seg = (tid & 3) << 4;
  ushort* op = out + (size_t)(bx + oc) * R + by + seg;
  s8v v0, v1;
#pragma unroll
  for (int j = 0; j < 8; ++j) {
    v0[j] = (short)f2bf(Ls[seg + j][oc]);
    v1[j] = (short)f2bf(Ls[seg + 8 + j][oc]);
  }
  *(s8v*)op = v0;
  *(s8v*)(op + 8) = v1;
}

__global__ __launch_bounds__(256) void transpose_cvt_kernel(
    const float* __restrict__ in, ushort* __restrict__ out, int R, int C)
{
  transpose_body(in + (size_t)blockIdx.z * R * C, out + (size_t)blockIdx.z * R * C, R, C);
}

// merged transpose for Wq/Wk/Wv/Wao (all 1024x1024): z selects source/dest
__global__ __launch_bounds__(256) void transpose_cvt4_kernel(
    const float* __restrict__ s0, const float* __restrict__ s1,
    const float* __restrict__ s2, const float* __restrict__ s3,
    ushort* __restrict__ dqkv, ushort* __restrict__ dao)
{
  const int z = blockIdx.z;
  const float* in = (z == 0) ? s0 : (z == 1) ? s1 : (z == 2) ? s2 : s3;
  ushort* out = (z < 3) ? (dqkv + (size_t)z * H_ * H_) : dao;
  transpose_body(in, out, H_, H_);
}

__global__ void concat3_kernel(const float* a, const float* b, const float* c,
                               float* __restrict__ o)
{
  const int t = blockIdx.x * 256 + threadIdx.x;   // 3072 total
  if (t < 1024) o[t] = a[t];
  else if (t < 2048) o[t] = b[t - 1024];
  else o[t] = c[t - 2048];
}

// ---------- fused scan + scatter (256-row tiles) ----------
__global__ __launch_bounds__(256) void scan_scatter_kernel(
    const int* __restrict__ idx, const int* __restrict__ cnt,
    int* __restrict__ offs, int* __restrict__ tb, int* __restrict__ lists)
{
  __shared__ int lcur[E_];
  const int tid = threadIdx.x;
  if (tid == 0) {
    int o = 0, tt = 0;
    for (int e = 0; e < E_; ++e) {
      offs[e] = o; lcur[e] = o; tb[e] = tt;
      o += cnt[e]; tt += (cnt[e] + 255) >> 8;
    }
    tb[E_] = tt;
  }
  __syncthreads();
  for (int t = tid; t < N_; t += 256) {
    const int e = idx[t];
    const int p = atomicAdd(&lcur[e], 1);
    lists[p] = t;
  }
}

// ---------- token gather ----------
__global__ __launch_bounds__(256) void gather_kernel(
    const ushort* __restrict__ X, const int* __restrict__ lists,
    ushort* __restrict__ Xg)
{
  const int r = (blockIdx.x << 1) + (threadIdx.x >> 7);
  const int c = (threadIdx.x & 127) << 3;
  const int tok = lists[r];
  *(s8v*)&Xg[(size_t)r * H_ + c] = *(const s8v*)&X[(size_t)tok * H_ + c];
}

// ---------- 256x256 MFMA GEMM, 8 waves, BK=32, 2-buf ------------------------
// ds_read -> MFMA with NO explicit lgkm drain: compiler emits counted
// lgkmcnt(N) so early MFMAs overlap later reads. Barrier B after MFMAs is
// WAR-safe: every ds_read feeds an MFMA, so reads retired before MFMA issue,
// hence before the wave signals barrier B; STG(cur) lands only after B.
__global__ __launch_bounds__(512, 2) void gemm256_kernel(
    const ushort* __restrict__ A, const ushort* __restrict__ Bt,
    const float* __restrict__ bias, ushort* __restrict__ Cout,
    const int M, const int N, const int K)
{
  __shared__ __align__(16) ushort Asm[2][4][256][8];
  __shared__ __align__(16) ushort Bsm[2][4][256][8];
  const int tid = threadIdx.x, w = tid >> 6, l = tid & 63;
  const int lq = l & 15, g = l >> 4;
  const int wm = w >> 2, wn = w & 3;
  const int nbx = N >> 8;
  const int nwg = nbx * (M >> 8);
  int id = blockIdx.y * nbx + blockIdx.x;
  id = (id & 7) * (nwg >> 3) + (id >> 3);     // bijective (nwg%8==0)
  const int m0 = (id / nbx) << 8, n0 = (id % nbx) << 8;

  const bool isB = (w >= 4);
  const int ks = w & 3;
  const ushort* gb = isB ? (Bt + (size_t)(n0 + l) * K + (ks << 3))
                         : (A + (size_t)(m0 + l) * K + (ks << 3));
  const ushort* p0 = gb;
  const ushort* p1 = gb + (size_t)64 * K;
  const ushort* p2 = gb + (size_t)128 * K;
  const ushort* p3 = gb + (size_t)192 * K;

  f4 acc[8][4] = {};
  const int nt = K >> 5;
#define STG(tt, buf) { const int kt_ = (tt) << 5;                          \
    ushort* d = isB ? &Bsm[buf][ks][0][0] : &Asm[buf][ks][0][0];           \
    gload16(p0 + kt_, d);          gload16(p1 + kt_, d + 64 * 8);          \
    gload16(p2 + kt_, d + 128 * 8); gload16(p3 + kt_, d + 192 * 8); }
  STG(0, 0);
  STG(1, 1);
  for (int t = 0; t < nt; ++t) {
    const int cur = t & 1;
    if (t + 1 < nt) { asm volatile("s_waitcnt vmcnt(4)" ::: "memory"); }
    else            { asm volatile("s_waitcnt vmcnt(0)" ::: "memory"); }
    __builtin_amdgcn_s_barrier();
    __builtin_amdgcn_sched_barrier(0);
    s8v af[8], bfv[4];
#pragma unroll
    for (int mi = 0; mi < 8; ++mi)
      af[mi] = *(const s8v*)&Asm[cur][g][(wm << 7) + (mi << 4) + lq][0];
#pragma unroll
    for (int ni = 0; ni < 4; ++ni)
      bfv[ni] = *(const s8v*)&Bsm[cur][g][(wn << 6) + (ni << 4) + lq][0];
#pragma unroll
    for (int mi = 0; mi < 8; ++mi)
#pragma unroll
      for (int ni = 0; ni < 4; ++ni)
        acc[mi][ni] = __builtin_amdgcn_mfma_f32_16x16x32_bf16(af[mi], bfv[ni], acc[mi][ni], 0, 0, 0);
    __builtin_amdgcn_sched_barrier(0);
    __builtin_amdgcn_s_barrier();
    if (t + 2 < nt) STG(t + 2, cur);
  }
#undef STG
  __syncthreads();
  ushort* st = (ushort*)Asm + (size_t)w * (16 * 72);
  float bs[4];
#pragma unroll
  for (int ni = 0; ni < 4; ++ni) bs[ni] = bias[n0 + (wn << 6) + (ni << 4) + lq];
#pragma unroll
  for (int mi = 0; mi < 8; ++mi) {
#pragma unroll
    for (int ni = 0; ni < 4; ++ni)
#pragma unroll
      for (int r = 0; r < 4; ++r)
        st[((g << 2) + r) * 72 + (ni << 4) + lq] = f2bf(acc[mi][ni][r] + bs[ni]);
#pragma unroll
    for (int q2 = 0; q2 < 2; ++q2) {
      const int r16 = l & 15, ch = (l >> 4) + (q2 << 2);
      const s8v vv = *(const s8v*)&st[r16 * 72 + (ch << 3)];
      *(s8v*)&Cout[(size_t)(m0 + (wm << 7) + (mi << 4) + r16) * N
                   + n0 + (wn << 6) + (ch << 3)] = vv;
    }
  }
}

// ---------- 128x128 MFMA GEMM (3-buf 1-barrier, no explicit drain) ----------
template <int KSPLIT>
__global__ __launch_bounds__(256, 3) void gemm128_kernel(
    const ushort* __restrict__ A, const ushort* __restrict__ Bt,
    const float* __restrict__ bias, float* __restrict__ Cout,
    const int M, const int N, const int K)
{
  __shared__ __align__(16) ushort Asm[3][4][128][8];
  __shared__ __align__(16) ushort Bsm[3][4][128][8];
  const int tid = threadIdx.x;
  const int w = tid >> 6, l = tid & 63;
  const int lq = l & 15, g = l >> 4;
  const int wm = w >> 1, wn = w & 1;
  const int nbx = N >> 7;
  const int nwg = nbx * (M >> 7);
  int id = blockIdx.y * nbx + blockIdx.x;
  id = (id & 7) * (nwg >> 3) + (id >> 3);
  const int m0 = (id / nbx) << 7, n0 = (id % nbx) << 7;
  const int Kspan = K / KSPLIT;
  const int kbase = (KSPLIT > 1) ? blockIdx.z * Kspan : 0;

  const ushort* a0 = A + (size_t)(m0 + l) * K + kbase + (w << 3);
  const ushort* a1 = a0 + (size_t)64 * K;
  const ushort* b0 = Bt + (size_t)(n0 + l) * K + kbase + (w << 3);
  const ushort* b1 = b0 + (size_t)64 * K;

  f4 acc[4][4] = {};
  const int nt = Kspan >> 5;
#define STAGE_G(tt, buf)                                   \
  { const int kt_ = (tt) << 5;                             \
    gload16(a0 + kt_, &Asm[buf][w][0][0]);                 \
    gload16(a1 + kt_, &Asm[buf][w][64][0]);                \
    gload16(b0 + kt_, &Bsm[buf][w][0][0]);                 \
    gload16(b1 + kt_, &Bsm[buf][w][64][0]); }
  STAGE_G(0, 0);
  STAGE_G(1, 1);
  int cur = 0, nxt2 = 2;
  for (int t = 0; t < nt; ++t) {
    if (t + 1 < nt) { asm volatile("s_waitcnt vmcnt(4)" ::: "memory"); }
    else            { asm volatile("s_waitcnt vmcnt(0)" ::: "memory"); }
    __builtin_amdgcn_s_barrier();
    __builtin_amdgcn_sched_barrier(0);
    if (t + 2 < nt) STAGE_G(t + 2, nxt2);
    s8v af[4], bfv[4];
#pragma unroll
    for (int mi = 0; mi < 4; ++mi)
      af[mi] = *(const s8v*)&Asm[cur][g][(wm << 6) + (mi << 4) + lq][0];
#pragma unroll
    for (int ni = 0; ni < 4; ++ni)
      bfv[ni] = *(const s8v*)&Bsm[cur][g][(wn << 6) + (ni << 4) + lq][0];
    // no explicit drain: compiler-counted lgkm waits interleave reads & MFMAs;
    // reads retire before this wave reaches the next-step barrier (MFMA deps).
#pragma unroll
    for (int mi = 0; mi < 4; ++mi)
#pragma unroll
      for (int ni = 0; ni < 4; ++ni)
        acc[mi][ni] = __builtin_amdgcn_mfma_f32_16x16x32_bf16(af[mi], bfv[ni], acc[mi][ni], 0, 0, 0);
    cur = (cur == 2) ? 0 : cur + 1;
    nxt2 = (nxt2 == 2) ? 0 : nxt2 + 1;
  }
#undef STAGE_G
  float* outf = Cout + (size_t)blockIdx.z * M * N;
#pragma unroll
  for (int ni = 0; ni < 4; ++ni) {
    const int col = n0 + (wn << 6) + (ni << 4) + lq;
    const float bs = (KSPLIT == 1 || blockIdx.z == 0) ? bias[col] : 0.f;
#pragma unroll
    for (int mi = 0; mi < 4; ++mi) {
      const int row = m0 + (wm << 6) + (mi << 4) + (g << 2);
#pragma unroll
      for (int r = 0; r < 4; ++r)
        outf[(size_t)(row + r) * N + col] = acc[mi][ni][r] + bs;
    }
  }
}

// ---------- 256x256 MoE expert GEMM (8 waves, 2-buf, no explicit drain) -----
__global__ __launch_bounds__(512, 2) void moe256_mfma_kernel(
    const ushort* __restrict__ Xg, const ushort* __restrict__ WeT,
    const float* __restrict__ be, const int* __restrict__ lists,
    const int* __restrict__ offs, const int* __restrict__ cnt,
    const int* __restrict__ tb, ushort* __restrict__ inter)
{
  __shared__ __align__(16) ushort Asm[2][4][256][8];
  __shared__ __align__(16) ushort Bsm[2][4][256][8];
  __shared__ int tokL[256];
  const int by = blockIdx.y;
  if (by >= tb[E_]) return;
  int e = 0;
#pragma unroll
  for (int t = 1; t < E_; ++t) if (by >= tb[t]) e = t;
  const int rt = by - tb[e];
  const int base = offs[e] + (rt << 8);
  const int nrows = cnt[e] - (rt << 8);
  const int tid = threadIdx.x;
  if (tid < 256) tokL[tid] = (tid < nrows) ? lists[base + tid] : -1;
  __syncthreads();
  const int w = tid >> 6, l = tid & 63;
  const int lq = l & 15, g = l >> 4;
  const int wm = w >> 2, wn = w & 3;
  const int n0 = blockIdx.x << 8;

  const bool isB = (w >= 4);
  const int ks = w & 3;
  const ushort* Wp = WeT + (size_t)e * I_ * H_;
  const ushort* p0;
  const ushort* p1;
  const ushort* p2;
  const ushort* p3;
  if (isB) {
    const ushort* gb = Wp + (size_t)(n0 + l) * H_ + (ks << 3);
    p0 = gb; p1 = gb + (size_t)64 * H_; p2 = gb + (size_t)128 * H_; p3 = gb + (size_t)192 * H_;
  } else {
    p0 = Xg + (size_t)min(base + l,       N_ - 1) * H_ + (ks << 3);
    p1 = Xg + (size_t)min(base + 64 + l,  N_ - 1) * H_ + (ks << 3);
    p2 = Xg + (size_t)min(base + 128 + l, N_ - 1) * H_ + (ks << 3);
    p3 = Xg + (size_t)min(base + 192 + l, N_ - 1) * H_ + (ks << 3);
  }

  f4 acc[8][4] = {};
#define STG(tt, buf) { const int kt_ = (tt) << 5;                          \
    ushort* d = isB ? &Bsm[buf][ks][0][0] : &Asm[buf][ks][0][0];           \
    gload16(p0 + kt_, d);          gload16(p1 + kt_, d + 64 * 8);          \
    gload16(p2 + kt_, d + 128 * 8); gload16(p3 + kt_, d + 192 * 8); }
  STG(0, 0);
  STG(1, 1);
  for (int t = 0; t < 32; ++t) {
    const int cur = t & 1;
    if (t + 1 < 32) { asm volatile("s_waitcnt vmcnt(4)" ::: "memory"); }
    else            { asm volatile("s_waitcnt vmcnt(0)" ::: "memory"); }
    __builtin_amdgcn_s_barrier();
    __builtin_amdgcn_sched_barrier(0);
    s8v af[8], bfv[4];
#pragma unroll
    for (int mi = 0; mi < 8; ++mi)
      af[mi] = *(const s8v*)&Asm[cur][g][(wm << 7) + (mi << 4) + lq][0];
#pragma unroll
    for (int ni = 0; ni < 4; ++ni)
      bfv[ni] = *(const s8v*)&Bsm[cur][g][(wn << 6) + (ni << 4) + lq][0];
#pragma unroll
    for (int mi = 0; mi < 8; ++mi)
#pragma unroll
      for (int ni = 0; ni < 4; ++ni)
        acc[mi][ni] = __builtin_amdgcn_mfma_f32_16x16x32_bf16(af[mi], bfv[ni], acc[mi][ni], 0, 0, 0);
    __builtin_amdgcn_sched_barrier(0);
    __builtin_amdgcn_s_barrier();
    if (t + 2 < 32) STG(t + 2, cur);
  }
#undef STG
  __syncthreads();
  ushort* st = (ushort*)Asm + (size_t)w * (16 * 72);
  float bs[4];
#pragma unroll
  for (int ni = 0; ni < 4; ++ni)
    bs[ni] = be[(size_t)e * I_ + n0 + (wn << 6) + (ni << 4) + lq];
#pragma unroll
  for (int mi = 0; mi < 8; ++mi) {
#pragma unroll
    for (int ni = 0; ni < 4; ++ni)
#pragma unroll
      for (int r = 0; r < 4; ++r)
        st[((g << 2) + r) * 72 + (ni << 4) + lq] = f2bf(gelu_f(acc[mi][ni][r] + bs[ni]));
#pragma unroll
    for (int q2 = 0; q2 < 2; ++q2) {
      const int r16 = l & 15, ch = (l >> 4) + (q2 << 2);
      const int tok = tokL[(wm << 7) + (mi << 4) + r16];
      if (tok >= 0) {
        const s8v vv = *(const s8v*)&st[r16 * 72 + (ch << 3)];
        *(s8v*)&inter[(size_t)tok * I_ + n0 + (wn << 6) + (ch << 3)] = vv;
      }
    }
  }
}

// ---------- MFMA flash attention: 8 waves, 128 queries/block (r17-verified) -
__global__ __launch_bounds__(512) void attn_mfma_kernel(
    const ushort* __restrict__ qkv, ushort* __restrict__ ctx)
{
  __shared__ __align__(16) ushort Ks[64 * 72];
  __shared__ __align__(16) ushort Vr[64 * 72];
  __shared__ __align__(16) ushort Vt[64 * 72];
  __shared__ __align__(16) ushort Ps[8][16 * 72];
  const int bid0 = blockIdx.x;
  const int bid  = ((bid0 & 7) << 6) + (bid0 >> 3);   // bijective (512%8==0)
  const int bh = bid >> 4, qt = bid & 15;             // 32 bh x 16 qtiles(128q)
  const int b = bh >> 4, h = bh & 15;
  const int tid = threadIdx.x, w = tid >> 6, l = tid & 63;
  const int lq = l & 15, g = l >> 4;
  const size_t bS = (size_t)b * S_;
  const ushort* qb = qkv + bS * QKVLD + h * DH_;
  const ushort* kb = qb + 1024;
  const ushort* vb = qb + 2048;

  s8v qf0, qf1;
  {
    const ushort* qp = qb + (size_t)(qt * 128 + w * 16 + lq) * QKVLD;
    qf0 = *(const s8v*)(qp + (g << 3));
    qf1 = *(const s8v*)(qp + 32 + (g << 3));
  }

  f4 o0 = {0,0,0,0}, o1 = {0,0,0,0}, o2 = {0,0,0,0}, o3 = {0,0,0,0};
  float mrun = -3.0e38f, lrun = 0.f;

  const int skey = tid >> 3;           // staging: key row 0..63
  const int sd   = (tid & 7) << 3;     // staging: 16B chunk (8 ushorts)

  s8v kr0, vr0;                        // async staging registers
#define ALOAD(t_) {                                                        \
    kr0 = *(const s8v*)(kb + (size_t)((t_) * 64 + skey) * QKVLD + sd);     \
    vr0 = *(const s8v*)(vb + (size_t)((t_) * 64 + skey) * QKVLD + sd); }
#define AWRITE() {                                                         \
    *(s8v*)&Ks[skey * 72 + sd] = kr0;                                      \
    *(s8v*)&Vr[skey * 72 + sd] = vr0; }

  ALOAD(0); AWRITE();
  ALOAD(1);

  for (int kt = 0; kt < 32; ++kt) {
    asm volatile("s_waitcnt lgkmcnt(0)" ::: "memory");
    __builtin_amdgcn_sched_barrier(0);
    __builtin_amdgcn_s_barrier();            // A: tile kt fully in LDS
    __builtin_amdgcn_sched_barrier(0);

    // LDS transpose Vr[key][d] -> Vt[d][key]; thread: d=l, keys w*8..w*8+7
    {
      s8v t0;
#pragma unroll
      for (int j = 0; j < 8; ++j)
        t0[j] = (short)Vr[(w * 8 + j) * 72 + l];
      *(s8v*)&Vt[l * 72 + w * 8] = t0;
    }

    float s[16];
    __builtin_amdgcn_s_setprio(1);
#pragma unroll
    for (int st = 0; st < 4; ++st) {
      f4 acc = {0, 0, 0, 0};
      const s8v ka0 = *(const s8v*)&Ks[(st * 16 + lq) * 72 + (g << 3)];
      const s8v ka1 = *(const s8v*)&Ks[(st * 16 + lq) * 72 + 32 + (g << 3)];
      acc = __builtin_amdgcn_mfma_f32_16x16x32_bf16(ka0, qf0, acc, 0, 0, 0);
      acc = __builtin_amdgcn_mfma_f32_16x16x32_bf16(ka1, qf1, acc, 0, 0, 0);
      s[st * 4 + 0] = acc[0] * 0.125f; s[st * 4 + 1] = acc[1] * 0.125f;
      s[st * 4 + 2] = acc[2] * 0.125f; s[st * 4 + 3] = acc[3] * 0.125f;
    }
    __builtin_amdgcn_s_setprio(0);

    // online softmax with defer-max (THR=8)
    float tmax = s[0];
#pragma unroll
    for (int i = 1; i < 16; ++i) tmax = fmaxf(tmax, s[i]);
    tmax = fmaxf(tmax, __shfl_xor(tmax, 16));
    tmax = fmaxf(tmax, __shfl_xor(tmax, 32));
    if (!__all(tmax - mrun <= 8.f)) {
      const float mnew  = fmaxf(mrun, tmax);
      const float alpha = __expf(mrun - mnew);
      f4 av;
      av[0] = __shfl(alpha, g * 4 + 0); av[1] = __shfl(alpha, g * 4 + 1);
      av[2] = __shfl(alpha, g * 4 + 2); av[3] = __shfl(alpha, g * 4 + 3);
      o0 *= av; o1 *= av; o2 *= av; o3 *= av;
      lrun *= alpha; mrun = mnew;
    }
    float psum = 0.f;
#pragma unroll
    for (int i = 0; i < 16; ++i) { s[i] = __expf(s[i] - mrun); psum += s[i]; }
    psum += __shfl_xor(psum, 16); psum += __shfl_xor(psum, 32);
    lrun += psum;

    {
      ushort* pw = &Ps[w][lq * 72];
#pragma unroll
      for (int st = 0; st < 4; ++st) {
        *(u32*)&pw[st * 16 + g * 4 + 0] = pack_bf2(s[st * 4 + 0], s[st * 4 + 1]);
        *(u32*)&pw[st * 16 + g * 4 + 2] = pack_bf2(s[st * 4 + 2], s[st * 4 + 3]);
      }
    }
    asm volatile("s_waitcnt lgkmcnt(0)" ::: "memory");
    __builtin_amdgcn_sched_barrier(0);
    __builtin_amdgcn_s_barrier();            // B: Vt complete, Ks/Vr reads done
    __builtin_amdgcn_sched_barrier(0);

    __builtin_amdgcn_s_setprio(1);
#pragma unroll
    for (int ks = 0; ks < 2; ++ks) {
      const int kof = ks * 32 + (g << 3);
      const s8v pa = *(const s8v*)&Ps[w][lq * 72 + kof];
      const s8v v0 = *(const s8v*)&Vt[( 0 + lq) * 72 + kof];
      const s8v v1 = *(const s8v*)&Vt[(16 + lq) * 72 + kof];
      const s8v v2 = *(const s8v*)&Vt[(32 + lq) * 72 + kof];
      const s8v v3 = *(const s8v*)&Vt[(48 + lq) * 72 + kof];
      o0 = __builtin_amdgcn_mfma_f32_16x16x32_bf16(pa, v0, o0, 0, 0, 0);
      o1 = __builtin_amdgcn_mfma_f32_16x16x32_bf16(pa, v1, o1, 0, 0, 0);
      o2 = __builtin_amdgcn_mfma_f32_16x16x32_bf16(pa, v2, o2, 0, 0, 0);
      o3 = __builtin_amdgcn_mfma_f32_16x16x32_bf16(pa, v3, o3, 0, 0, 0);
    }
    __builtin_amdgcn_s_setprio(0);

    if (kt + 1 < 32) AWRITE();
    if (kt + 2 < 32) ALOAD(kt + 2);
  }
#undef ALOAD
#undef AWRITE

  const float inv = 1.f / lrun;
#pragma unroll
  for (int r = 0; r < 4; ++r) {
    const float li = __shfl(inv, g * 4 + r);
    ushort* op = ctx + (bS + (size_t)(qt * 128 + w * 16 + g * 4 + r)) * H_ + h * DH_ + lq;
    op[0]  = f2bf(o0[r] * li);
    op[16] = f2bf(o1[r] * li);
    op[32] = f2bf(o2[r] * li);
    op[48] = f2bf(o3[r] * li);
  }
}

// ---------- P-partial sum + fp32 residual add + LayerNorm ----------
template <int P>
__global__ __launch_bounds__(256) void add_ln_kernel(
    const float* __restrict__ a, const float* __restrict__ r,
    const float* __restrict__ g, const float* __restrict__ bta,
    float* __restrict__ out, ushort* __restrict__ ob)
{
  const int row = blockIdx.x, tid = threadIdx.x;
  const size_t base = (size_t)row * H_;
  const float4 xr = *(const float4*)(r + base + (tid << 2));
  float4 x = xr;
#pragma unroll
  for (int pp = 0; pp < P; ++pp) {
    const float4 xa = *(const float4*)(a + (size_t)pp * N_ * H_ + base + (tid << 2));
    x.x += xa.x; x.y += xa.y; x.z += xa.z; x.w += xa.w;
  }
  float s  = x.x + x.y + x.z + x.w;
  float ss = x.x * x.x + x.y * x.y + x.z * x.z + x.w * x.w;
#pragma unroll
  for (int off = 1; off < 64; off <<= 1) { s += __shfl_xor(s, off); ss += __shfl_xor(ss, off); }
  __shared__ float red[8];
  const int w = tid >> 6, ln = tid & 63;
  if (ln == 0) { red[w] = s; red[4 + w] = ss; }
  __syncthreads();
  const float S  = red[0] + red[1] + red[2] + red[3];
  const float SS = red[4] + red[5] + red[6] + red[7];
  const float mu  = S * (1.f / 1024.f);
  const float var = fmaxf(SS * (1.f / 1024.f) - mu * mu, 0.f);
  const float inv = rsqrtf(var + LN_EPS);
  const float4 gg = *(const float4*)&g[tid << 2];
  const float4 bb = *(const float4*)&bta[tid << 2];
  float4 y;
  y.x = (x.x - mu) * inv * gg.x + bb.x;
  y.y = (x.y - mu) * inv * gg.y + bb.y;
  y.z = (x.z - mu) * inv * gg.z + bb.z;
  y.w = (x.w - mu) * inv * gg.w + bb.w;
  *(float4*)&out[base + (tid << 2)] = y;
  if (ob) {
    ushort4 u;
    u.x = f2bf(y.x); u.y = f2bf(y.y); u.z = f2bf(y.z); u.w = f2bf(y.w);
    *(ushort4*)&ob[base + (tid << 2)] = u;
  }
}

// ---------- router (fp32 logits for argmax fidelity) ----------
__global__ __launch_bounds__(64) void router_kernel(
    const float* __restrict__ x, const float* __restrict__ rw,
    int* __restrict__ idx, int* __restrict__ cnt)
{
  const int t = blockIdx.x, lane = threadIdx.x;
  float acc[8] = {0.f};
  for (int c = 0; c < H_; c += 64) {
    const float xv = x[(size_t)t * H_ + c + lane];
    const float* wr = rw + (size_t)(c + lane) * E_;
    const float4 w0 = *(const float4*)wr;
    const float4 w1 = *(const float4*)(wr + 4);
    acc[0] += xv * w0.x; acc[1] += xv * w0.y; acc[2] += xv * w0.z; acc[3] += xv * w0.w;
    acc[4] += xv * w1.x; acc[5] += xv * w1.y; acc[6] += xv * w1.z; acc[7] += xv * w1.w;
  }
#pragma unroll
  for (int e = 0; e < E_; ++e) {
    float s = acc[e];
#pragma unroll
    for (int off = 1; off < 64; off <<= 1) s += __shfl_xor(s, off);
    acc[e] = s;
  }
  if (lane == 0) {
    int be_ = 0; float bv = acc[0];
#pragma unroll
    for (int e = 1; e < E_; ++e) if (acc[e] > bv) { bv = acc[e]; be_ = e; }
    idx[t] = be_;
    atomicAdd(&cnt[be_], 1);
  }
}

// ---------- launch ----------
extern "C" void kernel_launch(void* const* d_in, const int* in_sizes, int n_in,
                              void* d_out, int out_size, void* d_ws, size_t ws_size,
                              hipStream_t stream) {
  const float* x   = (const float*)d_in[0];
  const float* Wq  = (const float*)d_in[1];
  const float* bq  = (const float*)d_in[2];
  const float* Wk  = (const float*)d_in[3];
  const float* bk  = (const float*)d_in[4];
  const float* Wv  = (const float*)d_in[5];
  const float* bv  = (const float*)d_in[6];
  const float* Wao = (const float*)d_in[7];
  const float* bao = (const float*)d_in[8];
  const float* g1  = (const float*)d_in[9];
  const float* b1  = (const float*)d_in[10];
  const float* rw  = (const float*)d_in[11];
  const float* We  = (const float*)d_in[12];
  const float* be  = (const float*)d_in[13];
  const float* Wo  = (const float*)d_in[14];
  const float* bo  = (const float*)d_in[15];
  const float* g2  = (const float*)d_in[16];
  const float* b2  = (const float*)d_in[17];
  float* out = (float*)d_out;

  char* p = (char*)d_ws;
  int* idx    = (int*)p; p += (size_t)N_ * 4;
  int* cnt    = (int*)p; p += 8 * 4;
  int* offs   = (int*)p; p += 8 * 4;
  int* tb     = (int*)p; p += 16 * 4;
  int* lists  = (int*)p; p += (size_t)N_ * 4;
  p = (char*)(((uintptr_t)p + 255) & ~(uintptr_t)255);
  const size_t NH = (size_t)N_ * H_;
  ushort* xb     = (ushort*)p; p += NH * 2;                 // x bf16; reused as Xg
  ushort* qkvb   = (ushort*)p;                              // fused qkv bf16 ...
  float*  woPart = (float*)p;  p += (size_t)N_ * QKVLD * 2; // ... reused: Wo partials x2
  ushort* ctxb   = (ushort*)p; p += NH * 2;                 // attn ctx bf16
  float*  attn   = (float*)p;  p += NH * 4;                 // LN1 out fp32
  ushort* attnb  = (ushort*)p; p += NH * 2;                 // LN1 out bf16
  ushort* interb = (ushort*)p;                              // MoE inter bf16 ...
  float*  aoPart = (float*)p;  p += (size_t)N_ * I_ * 2;    // ... reused: AO partials x2
  ushort* WqkvT  = (ushort*)p; p += (size_t)QKVLD * H_ * 2; // [3072][1024]
  ushort* WaoT   = (ushort*)p; p += (size_t)H_ * H_ * 2;    // [1024][1024]
  ushort* WoT    = (ushort*)p; p += (size_t)H_ * I_ * 2;    // [1024][4096]
  ushort* WeT    = (ushort*)p; p += (size_t)E_ * I_ * H_ * 2; // [8][4096][1024]
  float*  bqkv   = (float*)p;  p += QKVLD * 4;
  ushort* Xg     = xb;                                      // expert-sorted tokens

  const dim3 blk(256);
  const dim3 blk512(512);

  cvt_bf16_kernel<<<(N_ * H_ / 8 + 255) / 256, blk, 0, stream>>>(x, xb, N_ * H_ / 8, cnt);
  concat3_kernel<<<QKVLD / 256, blk, 0, stream>>>(bq, bk, bv, bqkv);
  transpose_cvt4_kernel<<<dim3(16, 16, 4), blk, 0, stream>>>(Wq, Wk, Wv, Wao, WqkvT, WaoT);
  transpose_cvt_kernel<<<dim3(16, 64, 1), blk, 0, stream>>>(Wo, WoT, I_, H_);
  transpose_cvt_kernel<<<dim3(64, 16, 8), blk, 0, stream>>>(We, WeT, H_, I_);

  gemm256_kernel<<<dim3(QKVLD / 256, N_ / 256), blk512, 0, stream>>>(
      xb, WqkvT, bqkv, qkvb, N_, QKVLD, H_);
  attn_mfma_kernel<<<512, blk512, 0, stream>>>(qkvb, ctxb);
  gemm128_kernel<2><<<dim3(H_ / 128, N_ / 128, 2), blk, 0, stream>>>(
      ctxb, WaoT, bao, aoPart, N_, H_, H_);
  add_ln_kernel<2><<<N_, blk, 0, stream>>>(aoPart, x, g1, b1, attn, attnb);
  router_kernel<<<N_, 64, 0, stream>>>(attn, rw, idx, cnt);
  scan_scatter_kernel<<<1, blk, 0, stream>>>(idx, cnt, offs, tb, lists);
  gather_kernel<<<N_ / 2, blk, 0, stream>>>(attnb, lists, Xg);
  moe256_mfma_kernel<<<dim3(I_ / 256, N_ / 256 + E_), blk512, 0, stream>>>(
      Xg, WeT, be, lists, offs, cnt, tb, interb);
  gemm128_kernel<2><<<dim3(H_ / 128, N_ / 128, 2), blk, 0, stream>>>(
      interb, WoT, bo, woPart, N_, H_, I_);
  add_ln_kernel<2><<<N_, blk, 0, stream>>>(woPart, attn, g2, b2, out, (ushort*)nullptr);
}

// Round 19
// 472.234 us; speedup vs baseline: 1.0255x; 1.0255x over previous
//
#include <hip/hip_runtime.h>
#include <hip/hip_bf16.h>
#include <cstdint>

#define H_  1024
#define NH_ 16
#define DH_ 64
#define I_  4096
#define E_  8
#define B_  2
#define S_  2048
#define N_  4096        // B_*S_
#define QKVLD 3072      // fused qkv row stride
#define LN_EPS 1e-12f

typedef __attribute__((ext_vector_type(4))) float f4;
typedef __attribute__((ext_vector_type(8))) short s8v;
typedef unsigned int u32;

// ---------- helpers ----------
__device__ __forceinline__ float bf2f(unsigned short u) {
  union { unsigned int i; float f; } c; c.i = ((unsigned int)u) << 16; return c.f;
}
__device__ __forceinline__ unsigned short f2bf(float f) {
  __hip_bfloat16 h = __float2bfloat16(f);
  return *reinterpret_cast<unsigned short*>(&h);
}
__device__ __forceinline__ u32 pack_bf2(float a, float b) {
  return (u32)f2bf(a) | ((u32)f2bf(b) << 16);
}
__device__ __forceinline__ float gelu_f(float x) {
  return 0.5f * x * (1.0f + erff(x * 0.70710678118f));   // exact GELU
}
__device__ __forceinline__ void gload16(const void* g, void* l) {
  __builtin_amdgcn_global_load_lds(
      (const __attribute__((address_space(1))) void*)g,
      (__attribute__((address_space(3))) void*)l, 16, 0, 0);
}

// ---------- fp32 -> bf16 elementwise (+ zero expert counters) ----------
__global__ __launch_bounds__(256) void cvt_bf16_kernel(
    const float* __restrict__ in, ushort* __restrict__ out, int n8, int* __restrict__ cnt)
{
  if (blockIdx.x == 0 && threadIdx.x < E_) cnt[threadIdx.x] = 0;
  const int t = blockIdx.x * 256 + threadIdx.x;
  if (t >= n8) return;
  const f4 x0 = *(const f4*)(in + (size_t)t * 8);
  const f4 x1 = *(const f4*)(in + (size_t)t * 8 + 4);
  s8v o;
#pragma unroll
  for (int j = 0; j < 4; ++j) { o[j] = (short)f2bf(x0[j]); o[4 + j] = (short)f2bf(x1[j]); }
  *(s8v*)(out + (size_t)t * 8) = o;
}

// ---------- fp32 [R][C] -> bf16 [C][R] transpose, 64x64 tile, 16B stores ----
__device__ __forceinline__ void transpose_body(
    const float* __restrict__ in, ushort* __restrict__ out, int R, int C)
{
  __shared__ float Ls[64][68];
  const int bx = blockIdx.x << 6;   // col base
  const int by = blockIdx.y << 6;   // row base
  const int tid = threadIdx.x;
  const int lr = tid >> 4, lc4 = (tid & 15) << 2;
  const float* ip = in + (size_t)(by + lr) * C + bx + lc4;
#pragma unroll
  for (int i = 0; i < 4; ++i)
    *(f4*)&Ls[lr + (i << 4)][lc4] = *(const f4*)(ip + (size_t)(i << 4) * C);
  __syncthreads();
  const int oc = tid >> 2, seg = (tid & 3) << 4;
  ushort* op = out + (size_t)(bx + oc) * R + by + seg;
  s8v v0, v1;
#pragma unroll
  for (int j = 0; j < 8; ++j) {
    v0[j] = (short)f2bf(Ls[seg + j][oc]);
    v1[j] = (short)f2bf(Ls[seg + 8 + j][oc]);
  }
  *(s8v*)op = v0;
  *(s8v*)(op + 8) = v1;
}

__global__ __launch_bounds__(256) void transpose_cvt_kernel(
    const float* __restrict__ in, ushort* __restrict__ out, int R, int C)
{
  transpose_body(in + (size_t)blockIdx.z * R * C, out + (size_t)blockIdx.z * R * C, R, C);
}

// merged transpose for Wq/Wk/Wv/Wao (all 1024x1024): z selects source/dest
__global__ __launch_bounds__(256) void transpose_cvt4_kernel(
    const float* __restrict__ s0, const float* __restrict__ s1,
    const float* __restrict__ s2, const float* __restrict__ s3,
    ushort* __restrict__ dqkv, ushort* __restrict__ dao)
{
  const int z = blockIdx.z;
  const float* in = (z == 0) ? s0 : (z == 1) ? s1 : (z == 2) ? s2 : s3;
  ushort* out = (z < 3) ? (dqkv + (size_t)z * H_ * H_) : dao;
  transpose_body(in, out, H_, H_);
}

__global__ void concat3_kernel(const float* a, const float* b, const float* c,
                               float* __restrict__ o)
{
  const int t = blockIdx.x * 256 + threadIdx.x;   // 3072 total
  if (t < 1024) o[t] = a[t];
  else if (t < 2048) o[t] = b[t - 1024];
  else o[t] = c[t - 2048];
}

// ---------- fused scan + scatter (256-row tiles) ----------
__global__ __launch_bounds__(256) void scan_scatter_kernel(
    const int* __restrict__ idx, const int* __restrict__ cnt,
    int* __restrict__ offs, int* __restrict__ tb, int* __restrict__ lists)
{
  __shared__ int lcur[E_];
  const int tid = threadIdx.x;
  if (tid == 0) {
    int o = 0, tt = 0;
    for (int e = 0; e < E_; ++e) {
      offs[e] = o; lcur[e] = o; tb[e] = tt;
      o += cnt[e]; tt += (cnt[e] + 255) >> 8;
    }
    tb[E_] = tt;
  }
  __syncthreads();
  for (int t = tid; t < N_; t += 256) {
    const int e = idx[t];
    const int p = atomicAdd(&lcur[e], 1);
    lists[p] = t;
  }
}

// ---------- token gather ----------
__global__ __launch_bounds__(256) void gather_kernel(
    const ushort* __restrict__ X, const int* __restrict__ lists,
    ushort* __restrict__ Xg)
{
  const int r = (blockIdx.x << 1) + (threadIdx.x >> 7);
  const int c = (threadIdx.x & 127) << 3;
  const int tok = lists[r];
  *(s8v*)&Xg[(size_t)r * H_ + c] = *(const s8v*)&X[(size_t)tok * H_ + c];
}

// ---------- 256x256 MFMA GEMM, 8 waves, BK=32, 2-buf (r17-verified sync) ----
__global__ __launch_bounds__(512, 2) void gemm256_kernel(
    const ushort* __restrict__ A, const ushort* __restrict__ Bt,
    const float* __restrict__ bias, ushort* __restrict__ Cout,
    const int M, const int N, const int K)
{
  __shared__ __align__(16) ushort Asm[2][4][256][8];
  __shared__ __align__(16) ushort Bsm[2][4][256][8];
  const int tid = threadIdx.x, w = tid >> 6, l = tid & 63;
  const int lq = l & 15, g = l >> 4;
  const int wm = w >> 2, wn = w & 3;
  const int nbx = N >> 8;
  const int nwg = nbx * (M >> 8);
  int id = blockIdx.y * nbx + blockIdx.x;
  id = (id & 7) * (nwg >> 3) + (id >> 3);     // bijective (nwg%8==0)
  const int m0 = (id / nbx) << 8, n0 = (id % nbx) << 8;

  const bool isB = (w >= 4);
  const int ks = w & 3;
  const ushort* gb = isB ? (Bt + (size_t)(n0 + l) * K + (ks << 3))
                         : (A + (size_t)(m0 + l) * K + (ks << 3));
  const ushort* p0 = gb;
  const ushort* p1 = gb + (size_t)64 * K;
  const ushort* p2 = gb + (size_t)128 * K;
  const ushort* p3 = gb + (size_t)192 * K;

  f4 acc[8][4] = {};
  const int nt = K >> 5;
#define STG(tt, buf) { const int kt_ = (tt) << 5;                          \
    ushort* d = isB ? &Bsm[buf][ks][0][0] : &Asm[buf][ks][0][0];           \
    gload16(p0 + kt_, d);          gload16(p1 + kt_, d + 64 * 8);          \
    gload16(p2 + kt_, d + 128 * 8); gload16(p3 + kt_, d + 192 * 8); }
  STG(0, 0);
  STG(1, 1);
  for (int t = 0; t < nt; ++t) {
    const int cur = t & 1;
    if (t + 1 < nt) { asm volatile("s_waitcnt vmcnt(4)" ::: "memory"); }
    else            { asm volatile("s_waitcnt vmcnt(0)" ::: "memory"); }
    __builtin_amdgcn_s_barrier();
    __builtin_amdgcn_sched_barrier(0);
    s8v af[8], bfv[4];
#pragma unroll
    for (int mi = 0; mi < 8; ++mi)
      af[mi] = *(const s8v*)&Asm[cur][g][(wm << 7) + (mi << 4) + lq][0];
#pragma unroll
    for (int ni = 0; ni < 4; ++ni)
      bfv[ni] = *(const s8v*)&Bsm[cur][g][(wn << 6) + (ni << 4) + lq][0];
    asm volatile("s_waitcnt lgkmcnt(0)" ::: "memory");
    __builtin_amdgcn_sched_barrier(0);
    __builtin_amdgcn_s_barrier();
    __builtin_amdgcn_sched_barrier(0);
    if (t + 2 < nt) STG(t + 2, cur);
#pragma unroll
    for (int mi = 0; mi < 8; ++mi)
#pragma unroll
      for (int ni = 0; ni < 4; ++ni)
        acc[mi][ni] = __builtin_amdgcn_mfma_f32_16x16x32_bf16(af[mi], bfv[ni], acc[mi][ni], 0, 0, 0);
  }
#undef STG
  __syncthreads();
  ushort* st = (ushort*)Asm + (size_t)w * (16 * 72);
  float bs[4];
#pragma unroll
  for (int ni = 0; ni < 4; ++ni) bs[ni] = bias[n0 + (wn << 6) + (ni << 4) + lq];
#pragma unroll
  for (int mi = 0; mi < 8; ++mi) {
#pragma unroll
    for (int ni = 0; ni < 4; ++ni)
#pragma unroll
      for (int r = 0; r < 4; ++r)
        st[((g << 2) + r) * 72 + (ni << 4) + lq] = f2bf(acc[mi][ni][r] + bs[ni]);
#pragma unroll
    for (int q2 = 0; q2 < 2; ++q2) {
      const int r16 = l & 15, ch = (l >> 4) + (q2 << 2);
      const s8v vv = *(const s8v*)&st[r16 * 72 + (ch << 3)];
      *(s8v*)&Cout[(size_t)(m0 + (wm << 7) + (mi << 4) + r16) * N
                   + n0 + (wn << 6) + (ch << 3)] = vv;
    }
  }
}

// ---------- 128x128 MFMA GEMM (r17-verified 3-buf 1-barrier), fp32 partials -
template <int KSPLIT>
__global__ __launch_bounds__(256, 3) void gemm128_kernel(
    const ushort* __restrict__ A, const ushort* __restrict__ Bt,
    const float* __restrict__ bias, float* __restrict__ Cout,
    const int M, const int N, const int K)
{
  __shared__ __align__(16) ushort Asm[3][4][128][8];
  __shared__ __align__(16) ushort Bsm[3][4][128][8];
  const int tid = threadIdx.x;
  const int w = tid >> 6, l = tid & 63;
  const int lq = l & 15, g = l >> 4;
  const int wm = w >> 1, wn = w & 1;
  const int nbx = N >> 7;
  const int nwg = nbx * (M >> 7);
  int id = blockIdx.y * nbx + blockIdx.x;
  id = (id & 7) * (nwg >> 3) + (id >> 3);
  const int m0 = (id / nbx) << 7, n0 = (id % nbx) << 7;
  const int Kspan = K / KSPLIT;
  const int kbase = (KSPLIT > 1) ? blockIdx.z * Kspan : 0;

  const ushort* a0 = A + (size_t)(m0 + l) * K + kbase + (w << 3);
  const ushort* a1 = a0 + (size_t)64 * K;
  const ushort* b0 = Bt + (size_t)(n0 + l) * K + kbase + (w << 3);
  const ushort* b1 = b0 + (size_t)64 * K;

  f4 acc[4][4] = {};
  const int nt = Kspan >> 5;
#define STAGE_G(tt, buf)                                   \
  { const int kt_ = (tt) << 5;                             \
    gload16(a0 + kt_, &Asm[buf][w][0][0]);                 \
    gload16(a1 + kt_, &Asm[buf][w][64][0]);                \
    gload16(b0 + kt_, &Bsm[buf][w][0][0]);                 \
    gload16(b1 + kt_, &Bsm[buf][w][64][0]); }
  STAGE_G(0, 0);
  STAGE_G(1, 1);
  int cur = 0, nxt2 = 2;
  for (int t = 0; t < nt; ++t) {
    if (t + 1 < nt) { asm volatile("s_waitcnt vmcnt(4)" ::: "memory"); }
    else            { asm volatile("s_waitcnt vmcnt(0)" ::: "memory"); }
    __builtin_amdgcn_s_barrier();
    __builtin_amdgcn_sched_barrier(0);
    if (t + 2 < nt) STAGE_G(t + 2, nxt2);
    s8v af[4], bfv[4];
#pragma unroll
    for (int mi = 0; mi < 4; ++mi)
      af[mi] = *(const s8v*)&Asm[cur][g][(wm << 6) + (mi << 4) + lq][0];
#pragma unroll
    for (int ni = 0; ni < 4; ++ni)
      bfv[ni] = *(const s8v*)&Bsm[cur][g][(wn << 6) + (ni << 4) + lq][0];
    asm volatile("s_waitcnt lgkmcnt(0)" ::: "memory");
    __builtin_amdgcn_sched_barrier(0);
#pragma unroll
    for (int mi = 0; mi < 4; ++mi)
#pragma unroll
      for (int ni = 0; ni < 4; ++ni)
        acc[mi][ni] = __builtin_amdgcn_mfma_f32_16x16x32_bf16(af[mi], bfv[ni], acc[mi][ni], 0, 0, 0);
    cur = (cur == 2) ? 0 : cur + 1;
    nxt2 = (nxt2 == 2) ? 0 : nxt2 + 1;
  }
#undef STAGE_G
  float* outf = Cout + (size_t)blockIdx.z * M * N;
#pragma unroll
  for (int ni = 0; ni < 4; ++ni) {
    const int col = n0 + (wn << 6) + (ni << 4) + lq;
    const float bs = (KSPLIT == 1 || blockIdx.z == 0) ? bias[col] : 0.f;
#pragma unroll
    for (int mi = 0; mi < 4; ++mi) {
      const int row = m0 + (wm << 6) + (mi << 4) + (g << 2);
#pragma unroll
      for (int r = 0; r < 4; ++r)
        outf[(size_t)(row + r) * N + col] = acc[mi][ni][r] + bs;
    }
  }
}

// ---------- 256x256 MoE expert GEMM (8 waves, 2-buf, r17-verified) ----------
__global__ __launch_bounds__(512, 2) void moe256_mfma_kernel(
    const ushort* __restrict__ Xg, const ushort* __restrict__ WeT,
    const float* __restrict__ be, const int* __restrict__ lists,
    const int* __restrict__ offs, const int* __restrict__ cnt,
    const int* __restrict__ tb, ushort* __restrict__ inter)
{
  __shared__ __align__(16) ushort Asm[2][4][256][8];
  __shared__ __align__(16) ushort Bsm[2][4][256][8];
  __shared__ int tokL[256];
  const int by = blockIdx.y;
  if (by >= tb[E_]) return;
  int e = 0;
#pragma unroll
  for (int t = 1; t < E_; ++t) if (by >= tb[t]) e = t;
  const int rt = by - tb[e];
  const int base = offs[e] + (rt << 8);
  const int nrows = cnt[e] - (rt << 8);
  const int tid = threadIdx.x;
  if (tid < 256) tokL[tid] = (tid < nrows) ? lists[base + tid] : -1;
  __syncthreads();
  const int w = tid >> 6, l = tid & 63;
  const int lq = l & 15, g = l >> 4;
  const int wm = w >> 2, wn = w & 3;
  const int n0 = blockIdx.x << 8;

  const bool isB = (w >= 4);
  const int ks = w & 3;
  const ushort* Wp = WeT + (size_t)e * I_ * H_;
  const ushort* p0;
  const ushort* p1;
  const ushort* p2;
  const ushort* p3;
  if (isB) {
    const ushort* gb = Wp + (size_t)(n0 + l) * H_ + (ks << 3);
    p0 = gb; p1 = gb + (size_t)64 * H_; p2 = gb + (size_t)128 * H_; p3 = gb + (size_t)192 * H_;
  } else {
    p0 = Xg + (size_t)min(base + l,       N_ - 1) * H_ + (ks << 3);
    p1 = Xg + (size_t)min(base + 64 + l,  N_ - 1) * H_ + (ks << 3);
    p2 = Xg + (size_t)min(base + 128 + l, N_ - 1) * H_ + (ks << 3);
    p3 = Xg + (size_t)min(base + 192 + l, N_ - 1) * H_ + (ks << 3);
  }

  f4 acc[8][4] = {};
#define STG(tt, buf) { const int kt_ = (tt) << 5;                          \
    ushort* d = isB ? &Bsm[buf][ks][0][0] : &Asm[buf][ks][0][0];           \
    gload16(p0 + kt_, d);          gload16(p1 + kt_, d + 64 * 8);          \
    gload16(p2 + kt_, d + 128 * 8); gload16(p3 + kt_, d + 192 * 8); }
  STG(0, 0);
  STG(1, 1);
  for (int t = 0; t < 32; ++t) {
    const int cur = t & 1;
    if (t + 1 < 32) { asm volatile("s_waitcnt vmcnt(4)" ::: "memory"); }
    else            { asm volatile("s_waitcnt vmcnt(0)" ::: "memory"); }
    __builtin_amdgcn_s_barrier();
    __builtin_amdgcn_sched_barrier(0);
    s8v af[8], bfv[4];
#pragma unroll
    for (int mi = 0; mi < 8; ++mi)
      af[mi] = *(const s8v*)&Asm[cur][g][(wm << 7) + (mi << 4) + lq][0];
#pragma unroll
    for (int ni = 0; ni < 4; ++ni)
      bfv[ni] = *(const s8v*)&Bsm[cur][g][(wn << 6) + (ni << 4) + lq][0];
    asm volatile("s_waitcnt lgkmcnt(0)" ::: "memory");
    __builtin_amdgcn_sched_barrier(0);
    __builtin_amdgcn_s_barrier();
    __builtin_amdgcn_sched_barrier(0);
    if (t + 2 < 32) STG(t + 2, cur);
#pragma unroll
    for (int mi = 0; mi < 8; ++mi)
#pragma unroll
      for (int ni = 0; ni < 4; ++ni)
        acc[mi][ni] = __builtin_amdgcn_mfma_f32_16x16x32_bf16(af[mi], bfv[ni], acc[mi][ni], 0, 0, 0);
  }
#undef STG
  __syncthreads();
  ushort* st = (ushort*)Asm + (size_t)w * (16 * 72);
  float bs[4];
#pragma unroll
  for (int ni = 0; ni < 4; ++ni)
    bs[ni] = be[(size_t)e * I_ + n0 + (wn << 6) + (ni << 4) + lq];
#pragma unroll
  for (int mi = 0; mi < 8; ++mi) {
#pragma unroll
    for (int ni = 0; ni < 4; ++ni)
#pragma unroll
      for (int r = 0; r < 4; ++r)
        st[((g << 2) + r) * 72 + (ni << 4) + lq] = f2bf(gelu_f(acc[mi][ni][r] + bs[ni]));
#pragma unroll
    for (int q2 = 0; q2 < 2; ++q2) {
      const int r16 = l & 15, ch = (l >> 4) + (q2 << 2);
      const int tok = tokL[(wm << 7) + (mi << 4) + r16];
      if (tok >= 0) {
        const s8v vv = *(const s8v*)&st[r16 * 72 + (ch << 3)];
        *(s8v*)&inter[(size_t)tok * I_ + n0 + (wn << 6) + (ch << 3)] = vv;
      }
    }
  }
}

// ---------- MFMA flash attention: 8 waves, 128 queries/block (r17-verified) -
__global__ __launch_bounds__(512) void attn_mfma_kernel(
    const ushort* __restrict__ qkv, ushort* __restrict__ ctx)
{
  __shared__ __align__(16) ushort Ks[64 * 72];
  __shared__ __align__(16) ushort Vr[64 * 72];
  __shared__ __align__(16) ushort Vt[64 * 72];
  __shared__ __align__(16) ushort Ps[8][16 * 72];
  const int bid0 = blockIdx.x;
  const int bid  = ((bid0 & 7) << 6) + (bid0 >> 3);   // bijective (512%8==0)
  const int bh = bid >> 4, qt = bid & 15;             // 32 bh x 16 qtiles(128q)
  const int b = bh >> 4, h = bh & 15;
  const int tid = threadIdx.x, w = tid >> 6, l = tid & 63;
  const int lq = l & 15, g = l >> 4;
  const size_t bS = (size_t)b * S_;
  const ushort* qb = qkv + bS * QKVLD + h * DH_;
  const ushort* kb = qb + 1024;
  const ushort* vb = qb + 2048;

  s8v qf0, qf1;
  {
    const ushort* qp = qb + (size_t)(qt * 128 + w * 16 + lq) * QKVLD;
    qf0 = *(const s8v*)(qp + (g << 3));
    qf1 = *(const s8v*)(qp + 32 + (g << 3));
  }

  f4 o0 = {0,0,0,0}, o1 = {0,0,0,0}, o2 = {0,0,0,0}, o3 = {0,0,0,0};
  float mrun = -3.0e38f, lrun = 0.f;

  const int skey = tid >> 3;           // staging: key row 0..63
  const int sd   = (tid & 7) << 3;     // staging: 16B chunk (8 ushorts)

  s8v kr0, vr0;                        // async staging registers
#define ALOAD(t_) {                                                        \
    kr0 = *(const s8v*)(kb + (size_t)((t_) * 64 + skey) * QKVLD + sd);     \
    vr0 = *(const s8v*)(vb + (size_t)((t_) * 64 + skey) * QKVLD + sd); }
#define AWRITE() {                                                         \
    *(s8v*)&Ks[skey * 72 + sd] = kr0;                                      \
    *(s8v*)&Vr[skey * 72 + sd] = vr0; }

  ALOAD(0); AWRITE();
  ALOAD(1);

  for (int kt = 0; kt < 32; ++kt) {
    asm volatile("s_waitcnt lgkmcnt(0)" ::: "memory");
    __builtin_amdgcn_sched_barrier(0);
    __builtin_amdgcn_s_barrier();            // A: tile kt fully in LDS
    __builtin_amdgcn_sched_barrier(0);

    // LDS transpose Vr[key][d] -> Vt[d][key]; thread: d=l, keys w*8..w*8+7
    {
      s8v t0;
#pragma unroll
      for (int j = 0; j < 8; ++j)
        t0[j] = (short)Vr[(w * 8 + j) * 72 + l];
      *(s8v*)&Vt[l * 72 + w * 8] = t0;
    }

    float s[16];
    __builtin_amdgcn_s_setprio(1);
#pragma unroll
    for (int st = 0; st < 4; ++st) {
      f4 acc = {0, 0, 0, 0};
      const s8v ka0 = *(const s8v*)&Ks[(st * 16 + lq) * 72 + (g << 3)];
      const s8v ka1 = *(const s8v*)&Ks[(st * 16 + lq) * 72 + 32 + (g << 3)];
      acc = __builtin_amdgcn_mfma_f32_16x16x32_bf16(ka0, qf0, acc, 0, 0, 0);
      acc = __builtin_amdgcn_mfma_f32_16x16x32_bf16(ka1, qf1, acc, 0, 0, 0);
      s[st * 4 + 0] = acc[0] * 0.125f; s[st * 4 + 1] = acc[1] * 0.125f;
      s[st * 4 + 2] = acc[2] * 0.125f; s[st * 4 + 3] = acc[3] * 0.125f;
    }
    __builtin_amdgcn_s_setprio(0);

    // online softmax with defer-max (THR=8)
    float tmax = s[0];
#pragma unroll
    for (int i = 1; i < 16; ++i) tmax = fmaxf(tmax, s[i]);
    tmax = fmaxf(tmax, __shfl_xor(tmax, 16));
    tmax = fmaxf(tmax, __shfl_xor(tmax, 32));
    if (!__all(tmax - mrun <= 8.f)) {
      const float mnew  = fmaxf(mrun, tmax);
      const float alpha = __expf(mrun - mnew);
      f4 av;
      av[0] = __shfl(alpha, g * 4 + 0); av[1] = __shfl(alpha, g * 4 + 1);
      av[2] = __shfl(alpha, g * 4 + 2); av[3] = __shfl(alpha, g * 4 + 3);
      o0 *= av; o1 *= av; o2 *= av; o3 *= av;
      lrun *= alpha; mrun = mnew;
    }
    float psum = 0.f;
#pragma unroll
    for (int i = 0; i < 16; ++i) { s[i] = __expf(s[i] - mrun); psum += s[i]; }
    psum += __shfl_xor(psum, 16); psum += __shfl_xor(psum, 32);
    lrun += psum;

    {
      ushort* pw = &Ps[w][lq * 72];
#pragma unroll
      for (int st = 0; st < 4; ++st) {
        *(u32*)&pw[st * 16 + g * 4 + 0] = pack_bf2(s[st * 4 + 0], s[st * 4 + 1]);
        *(u32*)&pw[st * 16 + g * 4 + 2] = pack_bf2(s[st * 4 + 2], s[st * 4 + 3]);
      }
    }
    asm volatile("s_waitcnt lgkmcnt(0)" ::: "memory");
    __builtin_amdgcn_sched_barrier(0);
    __builtin_amdgcn_s_barrier();            // B: Vt complete, Ks/Vr reads done
    __builtin_amdgcn_sched_barrier(0);

    __builtin_amdgcn_s_setprio(1);
#pragma unroll
    for (int ks = 0; ks < 2; ++ks) {
      const int kof = ks * 32 + (g << 3);
      const s8v pa = *(const s8v*)&Ps[w][lq * 72 + kof];
      const s8v v0 = *(const s8v*)&Vt[( 0 + lq) * 72 + kof];
      const s8v v1 = *(const s8v*)&Vt[(16 + lq) * 72 + kof];
      const s8v v2 = *(const s8v*)&Vt[(32 + lq) * 72 + kof];
      const s8v v3 = *(const s8v*)&Vt[(48 + lq) * 72 + kof];
      o0 = __builtin_amdgcn_mfma_f32_16x16x32_bf16(pa, v0, o0, 0, 0, 0);
      o1 = __builtin_amdgcn_mfma_f32_16x16x32_bf16(pa, v1, o1, 0, 0, 0);
      o2 = __builtin_amdgcn_mfma_f32_16x16x32_bf16(pa, v2, o2, 0, 0, 0);
      o3 = __builtin_amdgcn_mfma_f32_16x16x32_bf16(pa, v3, o3, 0, 0, 0);
    }
    __builtin_amdgcn_s_setprio(0);

    if (kt + 1 < 32) AWRITE();
    if (kt + 2 < 32) ALOAD(kt + 2);
  }
#undef ALOAD
#undef AWRITE

  const float inv = 1.f / lrun;
#pragma unroll
  for (int r = 0; r < 4; ++r) {
    const float li = __shfl(inv, g * 4 + r);
    ushort* op = ctx + (bS + (size_t)(qt * 128 + w * 16 + g * 4 + r)) * H_ + h * DH_ + lq;
    op[0]  = f2bf(o0[r] * li);
    op[16] = f2bf(o1[r] * li);
    op[32] = f2bf(o2[r] * li);
    op[48] = f2bf(o3[r] * li);
  }
}

// ---------- P-partial sum + fp32 residual + LayerNorm (+ fused router) ------
template <int P, bool ROUTE>
__global__ __launch_bounds__(256) void add_ln_kernel(
    const float* __restrict__ a, const float* __restrict__ r,
    const float* __restrict__ g, const float* __restrict__ bta,
    float* __restrict__ out, ushort* __restrict__ ob,
    const float* __restrict__ rw, int* __restrict__ idx, int* __restrict__ cnt)
{
  const int row = blockIdx.x, tid = threadIdx.x;
  const size_t base = (size_t)row * H_;
  const float4 xr = *(const float4*)(r + base + (tid << 2));
  float4 x = xr;
#pragma unroll
  for (int pp = 0; pp < P; ++pp) {
    const float4 xa = *(const float4*)(a + (size_t)pp * N_ * H_ + base + (tid << 2));
    x.x += xa.x; x.y += xa.y; x.z += xa.z; x.w += xa.w;
  }
  float s  = x.x + x.y + x.z + x.w;
  float ss = x.x * x.x + x.y * x.y + x.z * x.z + x.w * x.w;
#pragma unroll
  for (int off = 1; off < 64; off <<= 1) { s += __shfl_xor(s, off); ss += __shfl_xor(ss, off); }
  __shared__ float red[8];
  __shared__ float redr[4][8];
  const int w = tid >> 6, ln = tid & 63;
  if (ln == 0) { red[w] = s; red[4 + w] = ss; }
  __syncthreads();
  const float S  = red[0] + red[1] + red[2] + red[3];
  const float SS = red[4] + red[5] + red[6] + red[7];
  const float mu  = S * (1.f / 1024.f);
  const float var = fmaxf(SS * (1.f / 1024.f) - mu * mu, 0.f);
  const float inv = rsqrtf(var + LN_EPS);
  const float4 gg = *(const float4*)&g[tid << 2];
  const float4 bb = *(const float4*)&bta[tid << 2];
  float4 y;
  y.x = (x.x - mu) * inv * gg.x + bb.x;
  y.y = (x.y - mu) * inv * gg.y + bb.y;
  y.z = (x.z - mu) * inv * gg.z + bb.z;
  y.w = (x.w - mu) * inv * gg.w + bb.w;
  *(float4*)&out[base + (tid << 2)] = y;
  if (ob) {
    ushort4 u;
    u.x = f2bf(y.x); u.y = f2bf(y.y); u.z = f2bf(y.z); u.w = f2bf(y.w);
    *(ushort4*)&ob[base + (tid << 2)] = u;
  }
  if constexpr (ROUTE) {
    // logits[e] = sum_c y[c]*rw[c][e]; this thread holds cols 4*tid..4*tid+3
    float lacc[8];
#pragma unroll
    for (int e = 0; e < 8; ++e) lacc[e] = 0.f;
    const float yv[4] = {y.x, y.y, y.z, y.w};
#pragma unroll
    for (int j = 0; j < 4; ++j) {
      const float* wr = rw + (size_t)((tid << 2) + j) * E_;
      const f4 w0 = *(const f4*)wr;
      const f4 w1 = *(const f4*)(wr + 4);
      lacc[0] += yv[j] * w0[0]; lacc[1] += yv[j] * w0[1];
      lacc[2] += yv[j] * w0[2]; lacc[3] += yv[j] * w0[3];
      lacc[4] += yv[j] * w1[0]; lacc[5] += yv[j] * w1[1];
      lacc[6] += yv[j] * w1[2]; lacc[7] += yv[j] * w1[3];
    }
#pragma unroll
    for (int e = 0; e < 8; ++e) {
      float v = lacc[e];
#pragma unroll
      for (int off = 1; off < 64; off <<= 1) v += __shfl_xor(v, off);
      lacc[e] = v;
    }
    if (ln == 0) {
#pragma unroll
      for (int e = 0; e < 8; ++e) redr[w][e] = lacc[e];
    }
    __syncthreads();
    if (tid == 0) {
      int be_ = 0; float bv = -3.0e38f;
#pragma unroll
      for (int e = 0; e < 8; ++e) {
        const float v = redr[0][e] + redr[1][e] + redr[2][e] + redr[3][e];
        if (v > bv) { bv = v; be_ = e; }
      }
      idx[row] = be_;
      atomicAdd(&cnt[be_], 1);
    }
  }
}

// ---------- launch ----------
extern "C" void kernel_launch(void* const* d_in, const int* in_sizes, int n_in,
                              void* d_out, int out_size, void* d_ws, size_t ws_size,
                              hipStream_t stream) {
  const float* x   = (const float*)d_in[0];
  const float* Wq  = (const float*)d_in[1];
  const float* bq  = (const float*)d_in[2];
  const float* Wk  = (const float*)d_in[3];
  const float* bk  = (const float*)d_in[4];
  const float* Wv  = (const float*)d_in[5];
  const float* bv  = (const float*)d_in[6];
  const float* Wao = (const float*)d_in[7];
  const float* bao = (const float*)d_in[8];
  const float* g1  = (const float*)d_in[9];
  const float* b1  = (const float*)d_in[10];
  const float* rw  = (const float*)d_in[11];
  const float* We  = (const float*)d_in[12];
  const float* be  = (const float*)d_in[13];
  const float* Wo  = (const float*)d_in[14];
  const float* bo  = (const float*)d_in[15];
  const float* g2  = (const float*)d_in[16];
  const float* b2  = (const float*)d_in[17];
  float* out = (float*)d_out;

  char* p = (char*)d_ws;
  int* idx    = (int*)p; p += (size_t)N_ * 4;
  int* cnt    = (int*)p; p += 8 * 4;
  int* offs   = (int*)p; p += 8 * 4;
  int* tb     = (int*)p; p += 16 * 4;
  int* lists  = (int*)p; p += (size_t)N_ * 4;
  p = (char*)(((uintptr_t)p + 255) & ~(uintptr_t)255);
  const size_t NH = (size_t)N_ * H_;
  ushort* xb     = (ushort*)p; p += NH * 2;                 // x bf16; reused as Xg
  ushort* qkvb   = (ushort*)p;                              // fused qkv bf16 ...
  float*  woPart = (float*)p;  p += (size_t)N_ * QKVLD * 2; // ... reused: Wo partials x2
  ushort* ctxb   = (ushort*)p; p += NH * 2;                 // attn ctx bf16
  float*  attn   = (float*)p;  p += NH * 4;                 // LN1 out fp32
  ushort* attnb  = (ushort*)p; p += NH * 2;                 // LN1 out bf16
  ushort* interb = (ushort*)p;                              // MoE inter bf16 ...
  float*  aoPart = (float*)p;  p += (size_t)N_ * I_ * 2;    // ... reused: AO partials x2
  ushort* WqkvT  = (ushort*)p; p += (size_t)QKVLD * H_ * 2; // [3072][1024]
  ushort* WaoT   = (ushort*)p; p += (size_t)H_ * H_ * 2;    // [1024][1024]
  ushort* WoT    = (ushort*)p; p += (size_t)H_ * I_ * 2;    // [1024][4096]
  ushort* WeT    = (ushort*)p; p += (size_t)E_ * I_ * H_ * 2; // [8][4096][1024]
  float*  bqkv   = (float*)p;  p += QKVLD * 4;
  ushort* Xg     = xb;                                      // expert-sorted tokens

  const dim3 blk(256);
  const dim3 blk512(512);

  cvt_bf16_kernel<<<(N_ * H_ / 8 + 255) / 256, blk, 0, stream>>>(x, xb, N_ * H_ / 8, cnt);
  concat3_kernel<<<QKVLD / 256, blk, 0, stream>>>(bq, bk, bv, bqkv);
  transpose_cvt4_kernel<<<dim3(16, 16, 4), blk, 0, stream>>>(Wq, Wk, Wv, Wao, WqkvT, WaoT);
  transpose_cvt_kernel<<<dim3(16, 64, 1), blk, 0, stream>>>(Wo, WoT, I_, H_);
  transpose_cvt_kernel<<<dim3(64, 16, 8), blk, 0, stream>>>(We, WeT, H_, I_);

  gemm256_kernel<<<dim3(QKVLD / 256, N_ / 256), blk512, 0, stream>>>(
      xb, WqkvT, bqkv, qkvb, N_, QKVLD, H_);
  attn_mfma_kernel<<<512, blk512, 0, stream>>>(qkvb, ctxb);
  gemm128_kernel<2><<<dim3(H_ / 128, N_ / 128, 2), blk, 0, stream>>>(
      ctxb, WaoT, bao, aoPart, N_, H_, H_);
  add_ln_kernel<2, true><<<N_, blk, 0, stream>>>(
      aoPart, x, g1, b1, attn, attnb, rw, idx, cnt);
  scan_scatter_kernel<<<1, blk, 0, stream>>>(idx, cnt, offs, tb, lists);
  gather_kernel<<<N_ / 2, blk, 0, stream>>>(attnb, lists, Xg);
  moe256_mfma_kernel<<<dim3(I_ / 256, N_ / 256 + E_), blk512, 0, stream>>>(
      Xg, WeT, be, lists, offs, cnt, tb, interb);
  gemm128_kernel<2><<<dim3(H_ / 128, N_ / 128, 2), blk, 0, stream>>>(
      interb, WoT, bo, woPart, N_, H_, I_);
  add_ln_kernel<2, false><<<N_, blk, 0, stream>>>(
      woPart, attn, g2, b2, out, (ushort*)nullptr, nullptr, nullptr, nullptr);
}